// Round 15
// baseline (731.869 us; speedup 1.0000x reference)
//
#include <hip/hip_runtime.h>
#include <hip/hip_bf16.h>
#include <stdint.h>

#define NEXP 8
#define NROWS 8192
#define HID 2048
#define INTERN 2048
#define CAP 8192
#define KDIM 2048

typedef __attribute__((ext_vector_type(4))) float f32x4;
typedef __attribute__((ext_vector_type(8))) short bf16x8;

__device__ __forceinline__ unsigned short f2bf(float f) {
  union { float f; uint32_t u; } v; v.f = f;
  uint32_t u = v.u;
  uint32_t r = (u + 0x7fffu + ((u >> 16) & 1u)) >> 16;
  return (unsigned short)r;
}
__device__ __forceinline__ float bf2f(unsigned short u) {
  union { uint32_t u; float f; } v; v.u = (uint32_t)u << 16; return v.f;
}
__device__ __forceinline__ void gload16(const unsigned short* g, char* l) {
  __builtin_amdgcn_global_load_lds((const __attribute__((address_space(1))) void*)g,
                                   (__attribute__((address_space(3))) void*)l,
                                   16, 0, 0);
}

// ---------------- x fp32 -> bf16 ----------------
__global__ __launch_bounds__(256) void xcast_kernel(const float* __restrict__ x,
                                                    unsigned short* __restrict__ xb) {
  size_t i = ((size_t)blockIdx.x * 256 + threadIdx.x) * 8;
  size_t stride = (size_t)gridDim.x * 256 * 8;
  const size_t tot = (size_t)NROWS * HID;
  for (; i < tot; i += stride) {
    float4 a = *reinterpret_cast<const float4*>(x + i);
    float4 b = *reinterpret_cast<const float4*>(x + i + 4);
    unsigned short u[8];
    u[0] = f2bf(a.x); u[1] = f2bf(a.y); u[2] = f2bf(a.z); u[3] = f2bf(a.w);
    u[4] = f2bf(b.x); u[5] = f2bf(b.y); u[6] = f2bf(b.z); u[7] = f2bf(b.w);
    *reinterpret_cast<int4*>(xb + i) = *reinterpret_cast<const int4*>(u);
  }
}

// ---------------- router: top-2 of 8, renormalize, bucket per expert ----------------
// Also records each row's two slot codes (e*CAP+pos) for the combine pass.
__global__ void router_kernel(const float* __restrict__ probs,
                              int* __restrict__ cnt,
                              int* __restrict__ brow,
                              float* __restrict__ bw,
                              int* __restrict__ rslot) {
  int row = blockIdx.x * blockDim.x + threadIdx.x;
  if (row >= NROWS) return;
  float p[8];
#pragma unroll
  for (int j = 0; j < 8; j++) p[j] = probs[row * 8 + j];
  int i1 = 0; float v1 = p[0];
#pragma unroll
  for (int j = 1; j < 8; j++) if (p[j] > v1) { v1 = p[j]; i1 = j; }
  int i2 = -1; float v2 = -1e30f;
#pragma unroll
  for (int j = 0; j < 8; j++) if (j != i1 && p[j] > v2) { v2 = p[j]; i2 = j; }
  float s = v1 + v2;
  float w1 = v1 / s, w2 = v2 / s;
  int pos1 = atomicAdd(&cnt[i1], 1);
  brow[i1 * CAP + pos1] = row; bw[i1 * CAP + pos1] = w1;
  int pos2 = atomicAdd(&cnt[i2], 1);
  brow[i2 * CAP + pos2] = row; bw[i2 * CAP + pos2] = w2;
  rslot[row * 2 + 0] = i1 * CAP + pos1;
  rslot[row * 2 + 1] = i2 * CAP + pos2;
}

__global__ void offsets_kernel(const int* __restrict__ cnt, int* __restrict__ ofs) {
  if (threadIdx.x == 0 && blockIdx.x == 0) {
    int a = 0;
    for (int e = 0; e < NEXP; e++) { ofs[e] = a; a += cnt[e]; }
  }
}

// ---------------- transpose+cast: [E][K][N] f32 -> [E][N][K] bf16, 64x64 tiles ----------------
__global__ __launch_bounds__(256) void transpose_cast_kernel(const float* __restrict__ src,
                                                             unsigned short* __restrict__ dst) {
  __shared__ float tile[64][65];
  const int e = blockIdx.z;
  const int k0 = blockIdx.y * 64;
  const int n0 = blockIdx.x * 64;
  const float* s = src + (size_t)e * KDIM * KDIM;
  unsigned short* d = dst + (size_t)e * KDIM * KDIM;
  const int t = threadIdx.x;
  const int rr = t >> 4, cc = (t & 15) * 4;
#pragma unroll
  for (int i = 0; i < 4; i++) {
    float4 v = *reinterpret_cast<const float4*>(s + (size_t)(k0 + rr + i * 16) * KDIM + n0 + cc);
    tile[rr + i * 16][cc + 0] = v.x; tile[rr + i * 16][cc + 1] = v.y;
    tile[rr + i * 16][cc + 2] = v.z; tile[rr + i * 16][cc + 3] = v.w;
  }
  __syncthreads();
  const int n = t >> 2, kk0 = (t & 3) * 16;
  unsigned short u[16];
#pragma unroll
  for (int j = 0; j < 16; j++) u[j] = f2bf(tile[kk0 + j][n]);
  *reinterpret_cast<int4*>(d + (size_t)(n0 + n) * KDIM + k0 + kk0 + 0) = *reinterpret_cast<const int4*>(&u[0]);
  *reinterpret_cast<int4*>(d + (size_t)(n0 + n) * KDIM + k0 + kk0 + 8) = *reinterpret_cast<const int4*>(&u[8]);
}

// XCD-locality decode (T1, proven R10): L x-fastest; XCD ~ L%8.
// 8192-block variant: L' = (L&7)*1024 + (L>>3); e = L'>>10, mt = (L'&1023)>>4, nt = L'&15.
__device__ __forceinline__ void xcd_decode(int& e, int& mt, int& nt) {
  const int L = (blockIdx.z * 64 + blockIdx.y) * 16 + blockIdx.x;
  const int Lp = (L & 7) * 1024 + (L >> 3);
  e = Lp >> 10;
  mt = (Lp & 1023) >> 4;
  nt = Lp & 15;
}
// 4096-block variant for BN=256 gemm2: grid dim3(8,64,8); nt in [0,8).
__device__ __forceinline__ void xcd_decode_n256(int& e, int& mt, int& nt) {
  const int L = (blockIdx.z * 64 + blockIdx.y) * 8 + blockIdx.x;
  const int Lp = (L & 7) * 512 + (L >> 3);
  e = Lp >> 9;
  mt = (Lp & 511) >> 3;
  nt = Lp & 7;
}

// ---------------- fused GEMM13 (R10 verbatim): act = silu(Xe@fc1)*(Xe@fc3) ----------------
// 128x128 tile, BK=64, single-buffer, A staged once for both weights; 16x16x32 MFMA.
// Swizzle (128B rows): phys 16B-slot j = logical ^ (row&7); both-sides (rule #21).
__global__ __launch_bounds__(256, 2)
void gemm13_kernel(const unsigned short* __restrict__ A,
                   const unsigned short* __restrict__ W1,
                   const unsigned short* __restrict__ W3,
                   const int* __restrict__ cnt, const int* __restrict__ ofs,
                   const int* __restrict__ brow,
                   unsigned short* __restrict__ act) {
  int e, mt, nt;
  xcd_decode(e, mt, nt);
  const int Me = cnt[e];
  if (mt * 128 >= Me) return;
  __shared__ unsigned short As[128 * 64];    // 16 KB
  __shared__ unsigned short B1s[128 * 64];   // 16 KB
  __shared__ unsigned short B3s[128 * 64];   // 16 KB
  __shared__ int ridx[128];
  const int t = threadIdx.x, lane = t & 63, wave = t >> 6;
  const int oe = ofs[e];
  if (t < 128) {
    int sl = mt * 128 + t;
    ridx[t] = (sl < Me) ? brow[e * CAP + sl] : 0;
  }
  __syncthreads();

  const int srow = t >> 3;           // 0..31
  const int kg = ((t & 7) ^ (srow & 7)) * 8;   // pre-swizzled global k elem offset
  const unsigned short* pA0 = A + (size_t)ridx[srow +  0] * KDIM + kg;
  const unsigned short* pA1 = A + (size_t)ridx[srow + 32] * KDIM + kg;
  const unsigned short* pA2 = A + (size_t)ridx[srow + 64] * KDIM + kg;
  const unsigned short* pA3 = A + (size_t)ridx[srow + 96] * KDIM + kg;
  const unsigned short* pB0 = W1 + (size_t)e * KDIM * KDIM + (size_t)(nt * 128 + srow) * KDIM + kg;
  const ptrdiff_t dW = W3 - W1;
  char* dA  = (char*)As  + wave * 1024;
  char* dB1 = (char*)B1s + wave * 1024;
  char* dB3 = (char*)B3s + wave * 1024;

  const int wm = wave >> 1, wn = wave & 1;
  const int l15 = lane & 15, kq = lane >> 4;
  const int c0 = (kq * 16) ^ ((l15 & 7) << 4);
  const int aoff = (wm * 64 + l15) * 128;
  const int boff = (wn * 64 + l15) * 128;

  f32x4 acc1[4][4] = {};
  f32x4 acc3[4][4] = {};

  for (int k0 = 0; k0 < KDIM; k0 += 64) {
    gload16(pA0, dA);                    gload16(pA1, dA + 4096);
    gload16(pA2, dA + 8192);             gload16(pA3, dA + 12288);
    gload16(pB0,                dB1);    gload16(pB0 +  32 * KDIM, dB1 + 4096);
    gload16(pB0 + 64 * KDIM,    dB1 + 8192); gload16(pB0 + 96 * KDIM, dB1 + 12288);
    gload16(pB0 + dW,           dB3);    gload16(pB0 + dW + 32 * KDIM, dB3 + 4096);
    gload16(pB0 + dW + 64 * KDIM, dB3 + 8192); gload16(pB0 + dW + 96 * KDIM, dB3 + 12288);
    pA0 += 64; pA1 += 64; pA2 += 64; pA3 += 64; pB0 += 64;
    __syncthreads();

#pragma unroll
    for (int h = 0; h < 2; h++) {
      const int ch = h ? (c0 ^ 64) : c0;
      bf16x8 af[4], bf[4];
#pragma unroll
      for (int i = 0; i < 4; i++)
        af[i] = *reinterpret_cast<const bf16x8*>((const char*)As + aoff + i * 2048 + ch);
#pragma unroll
      for (int i = 0; i < 4; i++)
        bf[i] = *reinterpret_cast<const bf16x8*>((const char*)B1s + boff + i * 2048 + ch);
#pragma unroll
      for (int mi = 0; mi < 4; mi++)
#pragma unroll
        for (int ni = 0; ni < 4; ni++)
          acc1[mi][ni] = __builtin_amdgcn_mfma_f32_16x16x32_bf16(af[mi], bf[ni], acc1[mi][ni], 0, 0, 0);
#pragma unroll
      for (int i = 0; i < 4; i++)
        bf[i] = *reinterpret_cast<const bf16x8*>((const char*)B3s + boff + i * 2048 + ch);
#pragma unroll
      for (int mi = 0; mi < 4; mi++)
#pragma unroll
        for (int ni = 0; ni < 4; ni++)
          acc3[mi][ni] = __builtin_amdgcn_mfma_f32_16x16x32_bf16(af[mi], bf[ni], acc3[mi][ni], 0, 0, 0);
    }
    __syncthreads();
  }

  const int slot0 = oe + mt * 128;
#pragma unroll
  for (int mi = 0; mi < 4; mi++) {
#pragma unroll
    for (int ni = 0; ni < 4; ni++) {
      const int coln = nt * 128 + wn * 64 + ni * 16 + l15;
#pragma unroll
      for (int r = 0; r < 4; r++) {
        const int lrow = wm * 64 + mi * 16 + kq * 4 + r;
        if (mt * 128 + lrow < Me) {
          float h1 = acc1[mi][ni][r];
          float h3 = acc3[mi][ni][r];
          float sig = 1.f / (1.f + __expf(-h1));
          act[(size_t)(slot0 + lrow) * KDIM + coln] = f2bf(h1 * sig * h3);
        }
      }
    }
  }
}

// ---------------- GEMM2: slotbuf[slot] = rw * (act @ fc2), BM=128 x BN=256, BK=64 ----------
// 256 thr, 4 waves (2M x 2N; per-wave tile 64x128, acc[4][8]=128 regs). Per-wave K-step:
// 12 gloads + 24 ds_read_b128 + 64 MFMA -- gemm13's measured-830TF drain-amortization ratio.
// B rows are SEQUENTIAL weight rows: all 8 B-stage addrs are const offsets from one pB0
// (avoids R13's 8-gathered-pointer register pressure). Same proven swizzle + skeleton.
__global__ __launch_bounds__(256, 2)
void gemm2_kernel(const unsigned short* __restrict__ A,
                  const unsigned short* __restrict__ W,
                  const int* __restrict__ cnt, const int* __restrict__ ofs,
                  const float* __restrict__ bw,
                  float* __restrict__ slotbuf) {
  int e, mt, nt;
  xcd_decode_n256(e, mt, nt);
  const int Me = cnt[e];
  if (mt * 128 >= Me) return;
  __shared__ unsigned short As[128 * 64];   // 16 KB
  __shared__ unsigned short Bs[256 * 64];   // 32 KB
  __shared__ float rww[128];
  const int t = threadIdx.x, lane = t & 63, wave = t >> 6;
  const int oe = ofs[e];
  if (t < 128) {
    int sl = mt * 128 + t;
    rww[t] = (sl < Me) ? bw[e * CAP + sl] : 0.f;
  }
  __syncthreads();

  const int srow = t >> 3;                     // 0..31
  const int kg = ((t & 7) ^ (srow & 7)) * 8;   // pre-swizzled global k offset
  int s;
  const unsigned short *pA0, *pA1, *pA2, *pA3;
  s = mt * 128 + srow +  0; if (s >= Me) s = 0; pA0 = A + (size_t)(oe + s) * KDIM + kg;
  s = mt * 128 + srow + 32; if (s >= Me) s = 0; pA1 = A + (size_t)(oe + s) * KDIM + kg;
  s = mt * 128 + srow + 64; if (s >= Me) s = 0; pA2 = A + (size_t)(oe + s) * KDIM + kg;
  s = mt * 128 + srow + 96; if (s >= Me) s = 0; pA3 = A + (size_t)(oe + s) * KDIM + kg;
  const unsigned short* pB0 = W + (size_t)e * KDIM * KDIM + (size_t)(nt * 256 + srow) * KDIM + kg;
  char* dA = (char*)As + wave * 1024;
  char* dB = (char*)Bs + wave * 1024;

  const int wm = wave >> 1, wn = wave & 1;     // 2M x 2N; wave tile 64 x 128
  const int l15 = lane & 15, kq = lane >> 4;
  const int c0 = (kq * 16) ^ ((l15 & 7) << 4);
  const int aoff = (wm * 64 + l15) * 128;      // + mi*2048 (mi=0..3)
  const int boff = (wn * 128 + l15) * 128;     // + ni*2048 (ni=0..7)

  f32x4 acc[4][8] = {};

  for (int k0 = 0; k0 < KDIM; k0 += 64) {
    gload16(pA0, dA);         gload16(pA1, dA + 4096);
    gload16(pA2, dA + 8192);  gload16(pA3, dA + 12288);
    gload16(pB0,              dB);         gload16(pB0 +  32 * KDIM, dB + 4096);
    gload16(pB0 +  64 * KDIM, dB + 8192);  gload16(pB0 +  96 * KDIM, dB + 12288);
    gload16(pB0 + 128 * KDIM, dB + 16384); gload16(pB0 + 160 * KDIM, dB + 20480);
    gload16(pB0 + 192 * KDIM, dB + 24576); gload16(pB0 + 224 * KDIM, dB + 28672);
    pA0 += 64; pA1 += 64; pA2 += 64; pA3 += 64; pB0 += 64;
    __syncthreads();

#pragma unroll
    for (int h = 0; h < 2; h++) {
      const int ch = h ? (c0 ^ 64) : c0;
      bf16x8 af[4], bf[8];
#pragma unroll
      for (int i = 0; i < 4; i++)
        af[i] = *reinterpret_cast<const bf16x8*>((const char*)As + aoff + i * 2048 + ch);
#pragma unroll
      for (int i = 0; i < 8; i++)
        bf[i] = *reinterpret_cast<const bf16x8*>((const char*)Bs + boff + i * 2048 + ch);
#pragma unroll
      for (int mi = 0; mi < 4; mi++)
#pragma unroll
        for (int ni = 0; ni < 8; ni++)
          acc[mi][ni] = __builtin_amdgcn_mfma_f32_16x16x32_bf16(af[mi], bf[ni], acc[mi][ni], 0, 0, 0);
    }
    __syncthreads();
  }

  const int slot0 = oe + mt * 128;
#pragma unroll
  for (int mi = 0; mi < 4; mi++) {
#pragma unroll
    for (int ni = 0; ni < 8; ni++) {
      const int coln = nt * 256 + wn * 128 + ni * 16 + l15;
#pragma unroll
      for (int r = 0; r < 4; r++) {
        const int lrow = wm * 64 + mi * 16 + kq * 4 + r;
        if (mt * 128 + lrow < Me)
          slotbuf[(size_t)(slot0 + lrow) * HID + coln] = acc[mi][ni][r] * rww[lrow];
      }
    }
  }
}

// ---------------- combine: out[row] = slotbuf[slot1(row)] + slotbuf[slot2(row)] ------------
__global__ __launch_bounds__(256) void combine_kernel(const float* __restrict__ slotbuf,
                                                      const int* __restrict__ rslot,
                                                      const int* __restrict__ ofs,
                                                      float* __restrict__ out) {
  size_t i = ((size_t)blockIdx.x * 256 + threadIdx.x) * 4;
  const size_t stride = (size_t)gridDim.x * 256 * 4;
  const size_t tot = (size_t)NROWS * HID;
  for (; i < tot; i += stride) {
    const int row = (int)(i >> 11);          // HID = 2048
    const int c = (int)(i & (HID - 1));
    const int s1 = rslot[row * 2 + 0];
    const int s2 = rslot[row * 2 + 1];
    const int slot1 = ofs[s1 >> 13] + (s1 & (CAP - 1));
    const int slot2 = ofs[s2 >> 13] + (s2 & (CAP - 1));
    float4 a = *reinterpret_cast<const float4*>(slotbuf + (size_t)slot1 * HID + c);
    float4 b = *reinterpret_cast<const float4*>(slotbuf + (size_t)slot2 * HID + c);
    float4 o;
    o.x = a.x + b.x; o.y = a.y + b.y; o.z = a.z + b.z; o.w = a.w + b.w;
    *reinterpret_cast<float4*>(out + i) = o;
  }
}

extern "C" void kernel_launch(void* const* d_in, const int* in_sizes, int n_in,
                              void* d_out, int out_size, void* d_ws, size_t ws_size,
                              hipStream_t stream) {
  const float* x     = (const float*)d_in[0];
  const float* probs = (const float*)d_in[1];
  const float* fc1   = (const float*)d_in[2];
  const float* fc2   = (const float*)d_in[3];
  const float* fc3   = (const float*)d_in[4];
  float* out = (float*)d_out;

  char* ws = (char*)d_ws;
  const size_t WSZ = (size_t)NEXP * HID * INTERN * 2;  // 64 MiB per weight tensor
  unsigned short* wt1 = (unsigned short*)(ws);
  unsigned short* wt3 = (unsigned short*)(ws + WSZ);
  unsigned short* wt2 = (unsigned short*)(ws + 2 * WSZ);
  unsigned short* act = (unsigned short*)(ws + 3 * WSZ);   // 16384 x 2048 bf16
  unsigned short* xb  = (unsigned short*)(ws + 4 * WSZ);   // 8192 x 2048 bf16
  // slotbuf reuses wt1+wt3 (128 MiB = 16384 x 2048 f32), dead after gemm13 (stream-ordered)
  float* slotbuf = (float*)ws;
  char* rbase = ws + 4 * WSZ + (size_t)NROWS * HID * 2;
  int*   brow  = (int*)  (rbase);
  float* bw    = (float*)(rbase + (size_t)NEXP * CAP * 4);
  int*   cnt   = (int*)  (rbase + 2 * (size_t)NEXP * CAP * 4);
  int*   ofs   = (int*)  (rbase + 2 * (size_t)NEXP * CAP * 4 + 64);
  int*   rslot = (int*)  (rbase + 2 * (size_t)NEXP * CAP * 4 + 4096);   // 16384 ints

  hipMemsetAsync(cnt, 0, 64, stream);

  xcast_kernel<<<2048, 256, 0, stream>>>(x, xb);
  transpose_cast_kernel<<<dim3(32, 32, 8), 256, 0, stream>>>(fc1, wt1);
  transpose_cast_kernel<<<dim3(32, 32, 8), 256, 0, stream>>>(fc3, wt3);
  transpose_cast_kernel<<<dim3(32, 32, 8), 256, 0, stream>>>(fc2, wt2);
  router_kernel<<<NROWS / 256, 256, 0, stream>>>(probs, cnt, brow, bw, rslot);
  offsets_kernel<<<1, 64, 0, stream>>>(cnt, ofs);

  gemm13_kernel<<<dim3(16, 64, 8), 256, 0, stream>>>(xb, wt1, wt3, cnt, ofs, brow, act);
  gemm2_kernel<<<dim3(8, 64, 8), 256, 0, stream>>>(act, wt2, cnt, ofs, bw, slotbuf);
  combine_kernel<<<2048, 256, 0, stream>>>(slotbuf, rslot, ofs, out);
}

// Round 16
// 681.517 us; speedup vs baseline: 1.0739x; 1.0739x over previous
//
#include <hip/hip_runtime.h>
#include <hip/hip_bf16.h>
#include <stdint.h>

#define NEXP 8
#define NROWS 8192
#define HID 2048
#define INTERN 2048
#define CAP 8192
#define KDIM 2048

typedef __attribute__((ext_vector_type(4))) float f32x4;
typedef __attribute__((ext_vector_type(8))) short bf16x8;

__device__ __forceinline__ unsigned short f2bf(float f) {
  union { float f; uint32_t u; } v; v.f = f;
  uint32_t u = v.u;
  uint32_t r = (u + 0x7fffu + ((u >> 16) & 1u)) >> 16;
  return (unsigned short)r;
}
__device__ __forceinline__ float bf2f(unsigned short u) {
  union { uint32_t u; float f; } v; v.u = (uint32_t)u << 16; return v.f;
}
__device__ __forceinline__ void gload16(const unsigned short* g, char* l) {
  __builtin_amdgcn_global_load_lds((const __attribute__((address_space(1))) void*)g,
                                   (__attribute__((address_space(3))) void*)l,
                                   16, 0, 0);
}

// ---------------- x fp32 -> bf16 ----------------
__global__ __launch_bounds__(256) void xcast_kernel(const float* __restrict__ x,
                                                    unsigned short* __restrict__ xb) {
  size_t i = ((size_t)blockIdx.x * 256 + threadIdx.x) * 8;
  size_t stride = (size_t)gridDim.x * 256 * 8;
  const size_t tot = (size_t)NROWS * HID;
  for (; i < tot; i += stride) {
    float4 a = *reinterpret_cast<const float4*>(x + i);
    float4 b = *reinterpret_cast<const float4*>(x + i + 4);
    unsigned short u[8];
    u[0] = f2bf(a.x); u[1] = f2bf(a.y); u[2] = f2bf(a.z); u[3] = f2bf(a.w);
    u[4] = f2bf(b.x); u[5] = f2bf(b.y); u[6] = f2bf(b.z); u[7] = f2bf(b.w);
    *reinterpret_cast<int4*>(xb + i) = *reinterpret_cast<const int4*>(u);
  }
}

// ---------------- router: top-2 of 8, renormalize, bucket per expert ----------------
// Also records each row's two slot codes (e*CAP+pos) for the combine pass.
__global__ void router_kernel(const float* __restrict__ probs,
                              int* __restrict__ cnt,
                              int* __restrict__ brow,
                              float* __restrict__ bw,
                              int* __restrict__ rslot) {
  int row = blockIdx.x * blockDim.x + threadIdx.x;
  if (row >= NROWS) return;
  float p[8];
#pragma unroll
  for (int j = 0; j < 8; j++) p[j] = probs[row * 8 + j];
  int i1 = 0; float v1 = p[0];
#pragma unroll
  for (int j = 1; j < 8; j++) if (p[j] > v1) { v1 = p[j]; i1 = j; }
  int i2 = -1; float v2 = -1e30f;
#pragma unroll
  for (int j = 0; j < 8; j++) if (j != i1 && p[j] > v2) { v2 = p[j]; i2 = j; }
  float s = v1 + v2;
  float w1 = v1 / s, w2 = v2 / s;
  int pos1 = atomicAdd(&cnt[i1], 1);
  brow[i1 * CAP + pos1] = row; bw[i1 * CAP + pos1] = w1;
  int pos2 = atomicAdd(&cnt[i2], 1);
  brow[i2 * CAP + pos2] = row; bw[i2 * CAP + pos2] = w2;
  rslot[row * 2 + 0] = i1 * CAP + pos1;
  rslot[row * 2 + 1] = i2 * CAP + pos2;
}

__global__ void offsets_kernel(const int* __restrict__ cnt, int* __restrict__ ofs) {
  if (threadIdx.x == 0 && blockIdx.x == 0) {
    int a = 0;
    for (int e = 0; e < NEXP; e++) { ofs[e] = a; a += cnt[e]; }
  }
}

// ---------------- transpose+cast: [E][K][N] f32 -> [E][N][K] bf16, 64x64 tiles ----------------
__global__ __launch_bounds__(256) void transpose_cast_kernel(const float* __restrict__ src,
                                                             unsigned short* __restrict__ dst) {
  __shared__ float tile[64][65];
  const int e = blockIdx.z;
  const int k0 = blockIdx.y * 64;
  const int n0 = blockIdx.x * 64;
  const float* s = src + (size_t)e * KDIM * KDIM;
  unsigned short* d = dst + (size_t)e * KDIM * KDIM;
  const int t = threadIdx.x;
  const int rr = t >> 4, cc = (t & 15) * 4;
#pragma unroll
  for (int i = 0; i < 4; i++) {
    float4 v = *reinterpret_cast<const float4*>(s + (size_t)(k0 + rr + i * 16) * KDIM + n0 + cc);
    tile[rr + i * 16][cc + 0] = v.x; tile[rr + i * 16][cc + 1] = v.y;
    tile[rr + i * 16][cc + 2] = v.z; tile[rr + i * 16][cc + 3] = v.w;
  }
  __syncthreads();
  const int n = t >> 2, kk0 = (t & 3) * 16;
  unsigned short u[16];
#pragma unroll
  for (int j = 0; j < 16; j++) u[j] = f2bf(tile[kk0 + j][n]);
  *reinterpret_cast<int4*>(d + (size_t)(n0 + n) * KDIM + k0 + kk0 + 0) = *reinterpret_cast<const int4*>(&u[0]);
  *reinterpret_cast<int4*>(d + (size_t)(n0 + n) * KDIM + k0 + kk0 + 8) = *reinterpret_cast<const int4*>(&u[8]);
}

// XCD-locality decode (T1, proven R10): L x-fastest; XCD ~ L%8.
// L' = (L&7)*1024 + (L>>3) bijective on [0,8192); e = L'>>10, mt = (L'&1023)>>4, nt = L'&15.
__device__ __forceinline__ void xcd_decode(int& e, int& mt, int& nt) {
  const int L = (blockIdx.z * 64 + blockIdx.y) * 16 + blockIdx.x;
  const int Lp = (L & 7) * 1024 + (L >> 3);
  e = Lp >> 10;
  mt = (Lp & 1023) >> 4;
  nt = Lp & 15;
}

// ---------------- fused GEMM13 (R10 verbatim): act = silu(Xe@fc1)*(Xe@fc3) ----------------
// 128x128 tile, BK=64, single-buffer, A staged once for both weights; 16x16x32 MFMA.
// Swizzle (128B rows): phys 16B-slot j = logical ^ (row&7); both-sides (rule #21).
__global__ __launch_bounds__(256, 2)
void gemm13_kernel(const unsigned short* __restrict__ A,
                   const unsigned short* __restrict__ W1,
                   const unsigned short* __restrict__ W3,
                   const int* __restrict__ cnt, const int* __restrict__ ofs,
                   const int* __restrict__ brow,
                   unsigned short* __restrict__ act) {
  int e, mt, nt;
  xcd_decode(e, mt, nt);
  const int Me = cnt[e];
  if (mt * 128 >= Me) return;
  __shared__ unsigned short As[128 * 64];    // 16 KB
  __shared__ unsigned short B1s[128 * 64];   // 16 KB
  __shared__ unsigned short B3s[128 * 64];   // 16 KB
  __shared__ int ridx[128];
  const int t = threadIdx.x, lane = t & 63, wave = t >> 6;
  const int oe = ofs[e];
  if (t < 128) {
    int sl = mt * 128 + t;
    ridx[t] = (sl < Me) ? brow[e * CAP + sl] : 0;
  }
  __syncthreads();

  const int srow = t >> 3;           // 0..31
  const int kg = ((t & 7) ^ (srow & 7)) * 8;   // pre-swizzled global k elem offset
  const unsigned short* pA0 = A + (size_t)ridx[srow +  0] * KDIM + kg;
  const unsigned short* pA1 = A + (size_t)ridx[srow + 32] * KDIM + kg;
  const unsigned short* pA2 = A + (size_t)ridx[srow + 64] * KDIM + kg;
  const unsigned short* pA3 = A + (size_t)ridx[srow + 96] * KDIM + kg;
  const unsigned short* pB0 = W1 + (size_t)e * KDIM * KDIM + (size_t)(nt * 128 + srow) * KDIM + kg;
  const ptrdiff_t dW = W3 - W1;
  char* dA  = (char*)As  + wave * 1024;
  char* dB1 = (char*)B1s + wave * 1024;
  char* dB3 = (char*)B3s + wave * 1024;

  const int wm = wave >> 1, wn = wave & 1;
  const int l15 = lane & 15, kq = lane >> 4;
  const int c0 = (kq * 16) ^ ((l15 & 7) << 4);
  const int aoff = (wm * 64 + l15) * 128;
  const int boff = (wn * 64 + l15) * 128;

  f32x4 acc1[4][4] = {};
  f32x4 acc3[4][4] = {};

  for (int k0 = 0; k0 < KDIM; k0 += 64) {
    gload16(pA0, dA);                    gload16(pA1, dA + 4096);
    gload16(pA2, dA + 8192);             gload16(pA3, dA + 12288);
    gload16(pB0,                dB1);    gload16(pB0 +  32 * KDIM, dB1 + 4096);
    gload16(pB0 + 64 * KDIM,    dB1 + 8192); gload16(pB0 + 96 * KDIM, dB1 + 12288);
    gload16(pB0 + dW,           dB3);    gload16(pB0 + dW + 32 * KDIM, dB3 + 4096);
    gload16(pB0 + dW + 64 * KDIM, dB3 + 8192); gload16(pB0 + dW + 96 * KDIM, dB3 + 12288);
    pA0 += 64; pA1 += 64; pA2 += 64; pA3 += 64; pB0 += 64;
    __syncthreads();

#pragma unroll
    for (int h = 0; h < 2; h++) {
      const int ch = h ? (c0 ^ 64) : c0;
      bf16x8 af[4], bf[4];
#pragma unroll
      for (int i = 0; i < 4; i++)
        af[i] = *reinterpret_cast<const bf16x8*>((const char*)As + aoff + i * 2048 + ch);
#pragma unroll
      for (int i = 0; i < 4; i++)
        bf[i] = *reinterpret_cast<const bf16x8*>((const char*)B1s + boff + i * 2048 + ch);
#pragma unroll
      for (int mi = 0; mi < 4; mi++)
#pragma unroll
        for (int ni = 0; ni < 4; ni++)
          acc1[mi][ni] = __builtin_amdgcn_mfma_f32_16x16x32_bf16(af[mi], bf[ni], acc1[mi][ni], 0, 0, 0);
#pragma unroll
      for (int i = 0; i < 4; i++)
        bf[i] = *reinterpret_cast<const bf16x8*>((const char*)B3s + boff + i * 2048 + ch);
#pragma unroll
      for (int mi = 0; mi < 4; mi++)
#pragma unroll
        for (int ni = 0; ni < 4; ni++)
          acc3[mi][ni] = __builtin_amdgcn_mfma_f32_16x16x32_bf16(af[mi], bf[ni], acc3[mi][ni], 0, 0, 0);
    }
    __syncthreads();
  }

  const int slot0 = oe + mt * 128;
#pragma unroll
  for (int mi = 0; mi < 4; mi++) {
#pragma unroll
    for (int ni = 0; ni < 4; ni++) {
      const int coln = nt * 128 + wn * 64 + ni * 16 + l15;
#pragma unroll
      for (int r = 0; r < 4; r++) {
        const int lrow = wm * 64 + mi * 16 + kq * 4 + r;
        if (mt * 128 + lrow < Me) {
          float h1 = acc1[mi][ni][r];
          float h3 = acc3[mi][ni][r];
          float sig = 1.f / (1.f + __expf(-h1));
          act[(size_t)(slot0 + lrow) * KDIM + coln] = f2bf(h1 * sig * h3);
        }
      }
    }
  }
}

// ---------------- GEMM2 (R14 K-loop, bf16 slot-major epilogue) ----------------
// 128x128 tile, BK=64; stores scaled contribution slot-major as BF16:
// slotbuf[slot] = bf16(rw * (act@fc2)). Plain coalesced stores, no atomics.
// bf16 halves gemm2-write + combine-read traffic (~30us of streaming saved vs f32);
// error per contribution ~0.4% rel (~0.012 abs) before one f32 add -- negligible vs 0.925.
__global__ __launch_bounds__(256, 2)
void gemm2_kernel(const unsigned short* __restrict__ A,
                  const unsigned short* __restrict__ W,
                  const int* __restrict__ cnt, const int* __restrict__ ofs,
                  const float* __restrict__ bw,
                  unsigned short* __restrict__ slotbuf) {
  int e, mt, nt;
  xcd_decode(e, mt, nt);
  const int Me = cnt[e];
  if (mt * 128 >= Me) return;
  __shared__ unsigned short As[128 * 64];
  __shared__ unsigned short Bs[128 * 64];
  __shared__ float rww[128];
  const int t = threadIdx.x, lane = t & 63, wave = t >> 6;
  const int oe = ofs[e];
  if (t < 128) {
    int sl = mt * 128 + t;
    rww[t] = (sl < Me) ? bw[e * CAP + sl] : 0.f;
  }
  __syncthreads();

  const int srow = t >> 3;
  const int kg = ((t & 7) ^ (srow & 7)) * 8;
  int s;
  const unsigned short *pA0, *pA1, *pA2, *pA3;
  s = mt * 128 + srow +  0; if (s >= Me) s = 0; pA0 = A + (size_t)(oe + s) * KDIM + kg;
  s = mt * 128 + srow + 32; if (s >= Me) s = 0; pA1 = A + (size_t)(oe + s) * KDIM + kg;
  s = mt * 128 + srow + 64; if (s >= Me) s = 0; pA2 = A + (size_t)(oe + s) * KDIM + kg;
  s = mt * 128 + srow + 96; if (s >= Me) s = 0; pA3 = A + (size_t)(oe + s) * KDIM + kg;
  const unsigned short* pB0 = W + (size_t)e * KDIM * KDIM + (size_t)(nt * 128 + srow) * KDIM + kg;
  char* dA = (char*)As + wave * 1024;
  char* dB = (char*)Bs + wave * 1024;

  const int wm = wave >> 1, wn = wave & 1;
  const int l15 = lane & 15, kq = lane >> 4;
  const int c0 = (kq * 16) ^ ((l15 & 7) << 4);
  const int aoff = (wm * 64 + l15) * 128;
  const int boff = (wn * 64 + l15) * 128;

  f32x4 acc[4][4] = {};

  for (int k0 = 0; k0 < KDIM; k0 += 64) {
    gload16(pA0, dA);         gload16(pA1, dA + 4096);
    gload16(pA2, dA + 8192);  gload16(pA3, dA + 12288);
    gload16(pB0,             dB);        gload16(pB0 + 32 * KDIM, dB + 4096);
    gload16(pB0 + 64 * KDIM, dB + 8192); gload16(pB0 + 96 * KDIM, dB + 12288);
    pA0 += 64; pA1 += 64; pA2 += 64; pA3 += 64; pB0 += 64;
    __syncthreads();

#pragma unroll
    for (int h = 0; h < 2; h++) {
      const int ch = h ? (c0 ^ 64) : c0;
      bf16x8 af[4], bf[4];
#pragma unroll
      for (int i = 0; i < 4; i++) {
        af[i] = *reinterpret_cast<const bf16x8*>((const char*)As + aoff + i * 2048 + ch);
        bf[i] = *reinterpret_cast<const bf16x8*>((const char*)Bs + boff + i * 2048 + ch);
      }
#pragma unroll
      for (int mi = 0; mi < 4; mi++)
#pragma unroll
        for (int ni = 0; ni < 4; ni++)
          acc[mi][ni] = __builtin_amdgcn_mfma_f32_16x16x32_bf16(af[mi], bf[ni], acc[mi][ni], 0, 0, 0);
    }
    __syncthreads();
  }

  const int slot0 = oe + mt * 128;
#pragma unroll
  for (int mi = 0; mi < 4; mi++) {
#pragma unroll
    for (int ni = 0; ni < 4; ni++) {
      const int coln = nt * 128 + wn * 64 + ni * 16 + l15;
#pragma unroll
      for (int r = 0; r < 4; r++) {
        const int lrow = wm * 64 + mi * 16 + kq * 4 + r;
        if (mt * 128 + lrow < Me)
          slotbuf[(size_t)(slot0 + lrow) * HID + coln] = f2bf(acc[mi][ni][r] * rww[lrow]);
      }
    }
  }
}

// ---------------- combine: out[row] = slotbuf[slot1(row)] + slotbuf[slot2(row)] ------------
// slotbuf is bf16; 8 elements (16B) per slot per iter, f32 add, 32B f32 out.
__global__ __launch_bounds__(256) void combine_kernel(const unsigned short* __restrict__ slotbuf,
                                                      const int* __restrict__ rslot,
                                                      const int* __restrict__ ofs,
                                                      float* __restrict__ out) {
  size_t i = ((size_t)blockIdx.x * 256 + threadIdx.x) * 8;
  const size_t stride = (size_t)gridDim.x * 256 * 8;
  const size_t tot = (size_t)NROWS * HID;
  for (; i < tot; i += stride) {
    const int row = (int)(i >> 11);          // HID = 2048
    const int c = (int)(i & (HID - 1));
    const int s1 = rslot[row * 2 + 0];
    const int s2 = rslot[row * 2 + 1];
    const int slot1 = ofs[s1 >> 13] + (s1 & (CAP - 1));
    const int slot2 = ofs[s2 >> 13] + (s2 & (CAP - 1));
    ushort4 a0 = *reinterpret_cast<const ushort4*>(slotbuf + (size_t)slot1 * HID + c);
    ushort4 a1 = *reinterpret_cast<const ushort4*>(slotbuf + (size_t)slot1 * HID + c + 4);
    ushort4 b0 = *reinterpret_cast<const ushort4*>(slotbuf + (size_t)slot2 * HID + c);
    ushort4 b1 = *reinterpret_cast<const ushort4*>(slotbuf + (size_t)slot2 * HID + c + 4);
    float o[8];
    o[0] = bf2f(a0.x) + bf2f(b0.x); o[1] = bf2f(a0.y) + bf2f(b0.y);
    o[2] = bf2f(a0.z) + bf2f(b0.z); o[3] = bf2f(a0.w) + bf2f(b0.w);
    o[4] = bf2f(a1.x) + bf2f(b1.x); o[5] = bf2f(a1.y) + bf2f(b1.y);
    o[6] = bf2f(a1.z) + bf2f(b1.z); o[7] = bf2f(a1.w) + bf2f(b1.w);
    *reinterpret_cast<float4*>(out + i + 0) = *reinterpret_cast<const float4*>(&o[0]);
    *reinterpret_cast<float4*>(out + i + 4) = *reinterpret_cast<const float4*>(&o[4]);
  }
}

extern "C" void kernel_launch(void* const* d_in, const int* in_sizes, int n_in,
                              void* d_out, int out_size, void* d_ws, size_t ws_size,
                              hipStream_t stream) {
  const float* x     = (const float*)d_in[0];
  const float* probs = (const float*)d_in[1];
  const float* fc1   = (const float*)d_in[2];
  const float* fc2   = (const float*)d_in[3];
  const float* fc3   = (const float*)d_in[4];
  float* out = (float*)d_out;

  char* ws = (char*)d_ws;
  const size_t WSZ = (size_t)NEXP * HID * INTERN * 2;  // 64 MiB per weight tensor
  unsigned short* wt1 = (unsigned short*)(ws);
  unsigned short* wt3 = (unsigned short*)(ws + WSZ);
  unsigned short* wt2 = (unsigned short*)(ws + 2 * WSZ);
  unsigned short* act = (unsigned short*)(ws + 3 * WSZ);   // 16384 x 2048 bf16
  unsigned short* xb  = (unsigned short*)(ws + 4 * WSZ);   // 8192 x 2048 bf16
  // slotbuf reuses wt1 (64 MiB = 16384 x 2048 bf16), dead after gemm13 (stream-ordered)
  unsigned short* slotbuf = (unsigned short*)ws;
  char* rbase = ws + 4 * WSZ + (size_t)NROWS * HID * 2;
  int*   brow  = (int*)  (rbase);
  float* bw    = (float*)(rbase + (size_t)NEXP * CAP * 4);
  int*   cnt   = (int*)  (rbase + 2 * (size_t)NEXP * CAP * 4);
  int*   ofs   = (int*)  (rbase + 2 * (size_t)NEXP * CAP * 4 + 64);
  int*   rslot = (int*)  (rbase + 2 * (size_t)NEXP * CAP * 4 + 4096);   // 16384 ints

  hipMemsetAsync(cnt, 0, 64, stream);

  xcast_kernel<<<2048, 256, 0, stream>>>(x, xb);
  transpose_cast_kernel<<<dim3(32, 32, 8), 256, 0, stream>>>(fc1, wt1);
  transpose_cast_kernel<<<dim3(32, 32, 8), 256, 0, stream>>>(fc3, wt3);
  transpose_cast_kernel<<<dim3(32, 32, 8), 256, 0, stream>>>(fc2, wt2);
  router_kernel<<<NROWS / 256, 256, 0, stream>>>(probs, cnt, brow, bw, rslot);
  offsets_kernel<<<1, 64, 0, stream>>>(cnt, ofs);

  gemm13_kernel<<<dim3(16, 64, 8), 256, 0, stream>>>(xb, wt1, wt3, cnt, ofs, brow, act);
  gemm2_kernel<<<dim3(16, 64, 8), 256, 0, stream>>>(act, wt2, cnt, ofs, bw, slotbuf);
  combine_kernel<<<2048, 256, 0, stream>>>(slotbuf, rslot, ofs, out);
}